// Round 4
// baseline (239.117 us; speedup 1.0000x reference)
//
#include <hip/hip_runtime.h>
#include <hip/hip_bf16.h>

#define N_HALF 4096
#define M_TOT  8192
#define D      256
#define TJ     32          // j-rows staged in LDS per jt (32 -> 33.8 KB LDS, 3-4 blocks/CU)
#define JCHUNK 256         // j-cols per block (square symmetric tile)
#define NJT    (JCHUNK / TJ)
#define TTILE  (M_TOT / 256)          // 32 row/col tiles
#define NBLK   (TTILE * (TTILE + 1) / 2)   // 528 lower-triangle blocks

typedef __attribute__((ext_vector_type(8))) short bf16x8;
typedef __attribute__((ext_vector_type(4))) float f32x4;
typedef __attribute__((address_space(1))) const unsigned int ga_u32;
typedef __attribute__((address_space(3))) unsigned int ls_u32;

__device__ __forceinline__ float wave_reduce_sum(float v) {
    v += __shfl_xor(v, 1);
    v += __shfl_xor(v, 2);
    v += __shfl_xor(v, 4);
    v += __shfl_xor(v, 8);
    v += __shfl_xor(v, 16);
    v += __shfl_xor(v, 32);
    return v;
}

// Fused: normalize both rows of pair r, positive-pair dot, zero rowsum, zero out.
__global__ void k_prep(const float* __restrict__ zis, const float* __restrict__ zjs,
                       __hip_bfloat16* __restrict__ zn, float* __restrict__ rowsum,
                       float* __restrict__ pos_part, float* __restrict__ out) {
    int r = blockIdx.x;        // 0..4095
    int t = threadIdx.x;       // 0..255
    float zi = zis[(size_t)r * D + t];
    float zj = zjs[(size_t)r * D + t];
    float ssi = wave_reduce_sum(zi * zi);
    float ssj = wave_reduce_sum(zj * zj);
    float dd  = wave_reduce_sum(zi * zj);
    __shared__ float red[3][4];
    int w = t >> 6;
    if ((t & 63) == 0) { red[0][w] = ssi; red[1][w] = ssj; red[2][w] = dd; }
    __syncthreads();
    float ni = fmaxf(sqrtf(red[0][0] + red[0][1] + red[0][2] + red[0][3]), 1e-8f);
    float nj = fmaxf(sqrtf(red[1][0] + red[1][1] + red[1][2] + red[1][3]), 1e-8f);
    zn[(size_t)r * D + t]            = __float2bfloat16(zj / nj);
    zn[(size_t)(r + N_HALF) * D + t] = __float2bfloat16(zi / ni);
    if (t == 0) {
        float dot = red[2][0] + red[2][1] + red[2][2] + red[2][3];
        pos_part[r] = dot / (ni * nj) * 4.0f;   // each unordered pair 2x, /T -> *4
        rowsum[r] = 0.0f;
        rowsum[r + N_HALF] = 0.0f;
        if (r == 0) out[0] = 0.0f;
    }
}

// Symmetric-triangle k_main, round-2 structure (one 256x256 tile per block,
// 528 blocks) with RESIDENCY fix (round-3 post-mortem: wall = 7x pipe floor
// at 8 waves/CU; stalls, not work, dominate).
//   TJ=32  -> LDS 33.8 KB -> 3-4 blocks/CU co-resident
//   __launch_bounds__(256,3) -> 12 waves/CU; 768-block capacity >= 528
//   => all blocks resident from t=0 (no tail), cross-block stall hiding.
// Off-diag tiles scatter exp(sim) to rowsum[i] (row-reduce) AND rowsum[j]
// (col-reduce via LDS colsum, one flush at block end). Diag tiles full,
// col-side skipped. Exact partition of sim (ex-diagonal).
__global__ __launch_bounds__(256, 3)
void k_main(const __hip_bfloat16* __restrict__ znh, float* __restrict__ rowsum) {
    __shared__ __align__(16) ushort zj0[TJ * D];   // 16384 B
    __shared__ __align__(16) ushort zj1[TJ * D];   // 16384 B
    __shared__ float colsum[JCHUNK];               // 1024 B
    const ushort* zn = reinterpret_cast<const ushort*>(znh);
    int tid  = threadIdx.x;
    int wave = tid >> 6;
    int lane = tid & 63;
    int q    = lane >> 4;   // quad
    int li   = lane & 15;

    // triangle decode: b -> (bi, bj), bi <= bj, b = bj*(bj+1)/2 + bi
    int b = blockIdx.x;
    int t = (int)((sqrtf(8.0f * (float)b + 1.0f) - 1.0f) * 0.5f);
    while ((t + 1) * (t + 2) / 2 <= b) ++t;
    while (t * (t + 1) / 2 > b) --t;
    int bj = t;
    int bi = b - t * (t + 1) / 2;
    bool diag = (bi == bj);

    int i_base = bi * 256 + wave * 64;
    int j0     = bj * 256;

    // A fragment (16x16x32 bf16): A[m][k], m = lane&15, k = quad*8 + j
    bf16x8 afrag[4][8];
#pragma unroll
    for (int it = 0; it < 4; ++it) {
        const ushort* ap = zn + (((size_t)(i_base + it * 16 + li)) << 8) + q * 8;
#pragma unroll
        for (int kt = 0; kt < 8; ++kt)
            afrag[it][kt] = *reinterpret_cast<const bf16x8*>(ap + kt * 32);
    }

    float part[4][4];   // [i_tile][reg-row]
#pragma unroll
    for (int it = 0; it < 4; ++it)
#pragma unroll
        for (int r = 0; r < 4; ++r) part[it][r] = 0.0f;

    // Per-lane swizzled ds_read offsets (ushort units): both-sides XOR on 16B units.
    // Row r = jtile*16+li, r&7 == li&7, so the XOR term is jtile-invariant.
    int koff[8];
    {
        int swsh = (li & 7) << 3;
#pragma unroll
        for (int kt = 0; kt < 8; ++kt)
            koff[kt] = (((kt << 5) | (q << 3)) ^ swsh);
    }

    const ushort* rd = zj0;
    ushort*       wr = zj1;

    // staging: TJ=32 rows = 16 chunks of 1 KB; wave w issues chunks [w*4, w*4+4).
    // Chunk c holds rows 2c,2c+1. Lane l writes physical 16B-slot c*64+l:
    // row r = 2c + (l>>5), physical unit pu = l&31 -> fetch logical unit
    // u = pu ^ (r&7) from global so the read-side XOR lands on linear data.
#define STAGE(dstp, jbase)                                                       \
    {                                                                            \
        int c0 = wave * 4;                                                       \
        _Pragma("unroll")                                                        \
        for (int s = 0; s < 4; ++s) {                                            \
            int c = c0 + s;                                                      \
            int r = 2 * c + (lane >> 5);                                         \
            int u = (lane & 31) ^ (r & 7);                                       \
            const ushort* src = zn + (((size_t)((jbase) + r)) << 8) + (u << 3);  \
            __builtin_amdgcn_global_load_lds((ga_u32*)src,                       \
                                             (ls_u32*)((dstp) + c * 512),        \
                                             16, 0, 0);                          \
        }                                                                        \
    }

    STAGE(zj0, j0)
    colsum[tid] = 0.0f;
    __syncthreads();

    for (int jt = 0; jt < NJT; ++jt) {
        if (jt + 1 < NJT) STAGE(wr, j0 + (jt + 1) * TJ)

        float csum2[2];
#pragma unroll
        for (int jtile = 0; jtile < 2; ++jtile) {
            f32x4 acc[4] = {{0,0,0,0},{0,0,0,0},{0,0,0,0},{0,0,0,0}};
            const ushort* jrow = rd + (jtile << 12) + (li << 8);
#pragma unroll
            for (int kt = 0; kt < 8; ++kt) {
                bf16x8 bfr = *reinterpret_cast<const bf16x8*>(jrow + koff[kt]);
#pragma unroll
                for (int it = 0; it < 4; ++it)
                    acc[it] = __builtin_amdgcn_mfma_f32_16x16x32_bf16(
                        afrag[it][kt], bfr, acc[it], 0, 0, 0);
            }
            // C/D layout (m89-verified): col = lane&15, row = quad*4 + reg
            float cs = 0.0f;
#pragma unroll
            for (int it = 0; it < 4; ++it)
#pragma unroll
                for (int r = 0; r < 4; ++r) {
                    float e = __expf(acc[it][r] * 2.0f - 2.0f);
                    part[it][r] += e;
                    cs += e;
                }
            csum2[jtile] = cs;
        }
        // column partials: reduce over q (i-rows within wave), into LDS colsum.
#pragma unroll
        for (int jtile = 0; jtile < 2; ++jtile) {
            float v = csum2[jtile];
            v += __shfl_xor(v, 16);
            v += __shfl_xor(v, 32);
            if (q == 0) atomicAdd(&colsum[jt * TJ + jtile * 16 + li], v);
        }
        __syncthreads();   // staged tile ready; all reads of rd + colsum adds done
        const ushort* t0 = rd; rd = wr; wr = (ushort*)t0;
    }
#undef STAGE

    // Row-side: reduce across the 16 lanes holding different j-cols of the same rows.
#pragma unroll
    for (int it = 0; it < 4; ++it)
#pragma unroll
        for (int r = 0; r < 4; ++r) {
            float v = part[it][r];
            v += __shfl_xor(v, 1);
            v += __shfl_xor(v, 2);
            v += __shfl_xor(v, 4);
            v += __shfl_xor(v, 8);
            if (li == 0) atomicAdd(&rowsum[i_base + it * 16 + q * 4 + r], v);
        }

    // Col-side: transpose contribution rowsum[j] += sum_i exp(sim_ij).
    if (!diag) atomicAdd(&rowsum[j0 + tid], colsum[tid]);
}

// lse_i = 2 + log(rowsum_i - 1); loss = (sum lse - sum pos)/M.
// 32 blocks; per-block partial -> atomicAdd into pre-zeroed out[0].
__global__ void k_final(const float* __restrict__ rowsum, const float* __restrict__ pos_part,
                        float* __restrict__ out) {
    int idx = blockIdx.x * 256 + threadIdx.x;   // 0..8191
    float acc  = 2.0f + __logf(rowsum[idx] - 1.0f);
    float pacc = (idx < N_HALF) ? pos_part[idx] : 0.0f;
    acc  = wave_reduce_sum(acc);
    pacc = wave_reduce_sum(pacc);
    __shared__ float wsum[4], psum[4];
    int t = threadIdx.x;
    if ((t & 63) == 0) { wsum[t >> 6] = acc; psum[t >> 6] = pacc; }
    __syncthreads();
    if (t == 0) {
        float tot = wsum[0] + wsum[1] + wsum[2] + wsum[3]
                  - (psum[0] + psum[1] + psum[2] + psum[3]);
        atomicAdd(out, tot / (float)M_TOT);
    }
}

extern "C" void kernel_launch(void* const* d_in, const int* in_sizes, int n_in,
                              void* d_out, int out_size, void* d_ws, size_t ws_size,
                              hipStream_t stream) {
    const float* zis = (const float*)d_in[0];
    const float* zjs = (const float*)d_in[1];
    char* ws = (char*)d_ws;
    __hip_bfloat16* zn = (__hip_bfloat16*)ws;                         // 4 MB
    float* rowsum   = (float*)(ws + (size_t)M_TOT * D * 2);           // 32 KB
    float* pos_part = rowsum + M_TOT;                                 // 16 KB
    float* out = (float*)d_out;

    k_prep<<<N_HALF, 256, 0, stream>>>(zis, zjs, zn, rowsum, pos_part, out);
    k_main<<<NBLK, 256, 0, stream>>>(zn, rowsum);
    k_final<<<M_TOT / 256, 256, 0, stream>>>(rowsum, pos_part, out);
}

// Round 5
// 102.396 us; speedup vs baseline: 2.3352x; 2.3352x over previous
//
#include <hip/hip_runtime.h>
#include <hip/hip_bf16.h>

#define N_HALF 4096
#define M_TOT  8192
#define D      256
#define TJ     32          // j-rows staged in LDS per jt (33.8 KB LDS total)
#define JCHUNK 256         // j-cols per block (square symmetric tile)
#define NJT    (JCHUNK / TJ)
#define TTILE  (M_TOT / 256)          // 32 row/col tiles
#define NBLK   (TTILE * (TTILE + 1) / 2)   // 528 lower-triangle blocks

typedef __attribute__((ext_vector_type(8))) short bf16x8;
typedef __attribute__((ext_vector_type(4))) float f32x4;
typedef __attribute__((address_space(1))) const unsigned int ga_u32;
typedef __attribute__((address_space(3))) unsigned int ls_u32;

__device__ __forceinline__ float wave_reduce_sum(float v) {
    v += __shfl_xor(v, 1);
    v += __shfl_xor(v, 2);
    v += __shfl_xor(v, 4);
    v += __shfl_xor(v, 8);
    v += __shfl_xor(v, 16);
    v += __shfl_xor(v, 32);
    return v;
}

// Fused: normalize both rows of pair r, positive-pair dot, zero rowsum, zero out.
__global__ void k_prep(const float* __restrict__ zis, const float* __restrict__ zjs,
                       __hip_bfloat16* __restrict__ zn, float* __restrict__ rowsum,
                       float* __restrict__ pos_part, float* __restrict__ out) {
    int r = blockIdx.x;        // 0..4095
    int t = threadIdx.x;       // 0..255
    float zi = zis[(size_t)r * D + t];
    float zj = zjs[(size_t)r * D + t];
    float ssi = wave_reduce_sum(zi * zi);
    float ssj = wave_reduce_sum(zj * zj);
    float dd  = wave_reduce_sum(zi * zj);
    __shared__ float red[3][4];
    int w = t >> 6;
    if ((t & 63) == 0) { red[0][w] = ssi; red[1][w] = ssj; red[2][w] = dd; }
    __syncthreads();
    float ni = fmaxf(sqrtf(red[0][0] + red[0][1] + red[0][2] + red[0][3]), 1e-8f);
    float nj = fmaxf(sqrtf(red[1][0] + red[1][1] + red[1][2] + red[1][3]), 1e-8f);
    zn[(size_t)r * D + t]            = __float2bfloat16(zj / nj);
    zn[(size_t)(r + N_HALF) * D + t] = __float2bfloat16(zi / ni);
    if (t == 0) {
        float dot = red[2][0] + red[2][1] + red[2][2] + red[2][3];
        pos_part[r] = dot / (ni * nj) * 4.0f;   // each unordered pair 2x, /T -> *4
        rowsum[r] = 0.0f;
        rowsum[r + N_HALF] = 0.0f;
        if (r == 0) out[0] = 0.0f;
    }
}

// Symmetric-triangle k_main (528 blocks, one 256x256 tile each).
// Round-4 post-mortem: __launch_bounds__(256,3) capped unified VGPR+AGPR at
// ~170 -> afrag (128 VGPR) spilled to scratch -> 0.5 GB scratch traffic, 180us.
// Fix: (256,2) (proven 128-VGPR no-spill) and let HARDWARE residency come
// from resources: LDS 33.8 KB -> 4 blocks/CU, 128 VGPR -> 3-4 waves/SIMD.
// Capacity >= 768 >= 528 -> all blocks resident, no tail, cross-block stall hiding.
// Off-diag tiles scatter exp(sim) to rowsum[i] (row-reduce) AND rowsum[j]
// (col-reduce via LDS colsum, one flush at block end). Diag tiles full,
// col-side skipped. Exact partition of sim (ex-diagonal).
__global__ __launch_bounds__(256, 2)
void k_main(const __hip_bfloat16* __restrict__ znh, float* __restrict__ rowsum) {
    __shared__ __align__(16) ushort zj0[TJ * D];   // 16384 B
    __shared__ __align__(16) ushort zj1[TJ * D];   // 16384 B
    __shared__ float colsum[JCHUNK];               // 1024 B
    const ushort* zn = reinterpret_cast<const ushort*>(znh);
    int tid  = threadIdx.x;
    int wave = tid >> 6;
    int lane = tid & 63;
    int q    = lane >> 4;   // quad
    int li   = lane & 15;

    // triangle decode: b -> (bi, bj), bi <= bj, b = bj*(bj+1)/2 + bi
    int b = blockIdx.x;
    int t = (int)((sqrtf(8.0f * (float)b + 1.0f) - 1.0f) * 0.5f);
    while ((t + 1) * (t + 2) / 2 <= b) ++t;
    while (t * (t + 1) / 2 > b) --t;
    int bj = t;
    int bi = b - t * (t + 1) / 2;
    bool diag = (bi == bj);

    int i_base = bi * 256 + wave * 64;
    int j0     = bj * 256;

    // A fragment (16x16x32 bf16): A[m][k], m = lane&15, k = quad*8 + j
    bf16x8 afrag[4][8];
#pragma unroll
    for (int it = 0; it < 4; ++it) {
        const ushort* ap = zn + (((size_t)(i_base + it * 16 + li)) << 8) + q * 8;
#pragma unroll
        for (int kt = 0; kt < 8; ++kt)
            afrag[it][kt] = *reinterpret_cast<const bf16x8*>(ap + kt * 32);
    }

    float part[4][4];   // [i_tile][reg-row]
#pragma unroll
    for (int it = 0; it < 4; ++it)
#pragma unroll
        for (int r = 0; r < 4; ++r) part[it][r] = 0.0f;

    // Per-lane swizzled ds_read offsets (ushort units): both-sides XOR on 16B units.
    // Row r = jtile*16+li, r&7 == li&7, so the XOR term is jtile-invariant.
    int koff[8];
    {
        int swsh = (li & 7) << 3;
#pragma unroll
        for (int kt = 0; kt < 8; ++kt)
            koff[kt] = (((kt << 5) | (q << 3)) ^ swsh);
    }

    const ushort* rd = zj0;
    ushort*       wr = zj1;

    // staging: TJ=32 rows = 16 chunks of 1 KB; wave w issues chunks [w*4, w*4+4).
    // Chunk c holds rows 2c,2c+1. Lane l writes physical 16B-slot c*64+l:
    // row r = 2c + (l>>5), physical unit pu = l&31 -> fetch logical unit
    // u = pu ^ (r&7) from global so the read-side XOR lands on linear data.
#define STAGE(dstp, jbase)                                                       \
    {                                                                            \
        int c0 = wave * 4;                                                       \
        _Pragma("unroll")                                                        \
        for (int s = 0; s < 4; ++s) {                                            \
            int c = c0 + s;                                                      \
            int r = 2 * c + (lane >> 5);                                         \
            int u = (lane & 31) ^ (r & 7);                                       \
            const ushort* src = zn + (((size_t)((jbase) + r)) << 8) + (u << 3);  \
            __builtin_amdgcn_global_load_lds((ga_u32*)src,                       \
                                             (ls_u32*)((dstp) + c * 512),        \
                                             16, 0, 0);                          \
        }                                                                        \
    }

    STAGE(zj0, j0)
    colsum[tid] = 0.0f;
    __syncthreads();

    for (int jt = 0; jt < NJT; ++jt) {
        if (jt + 1 < NJT) STAGE(wr, j0 + (jt + 1) * TJ)

        float csum2[2];
#pragma unroll
        for (int jtile = 0; jtile < 2; ++jtile) {
            f32x4 acc[4] = {{0,0,0,0},{0,0,0,0},{0,0,0,0},{0,0,0,0}};
            const ushort* jrow = rd + (jtile << 12) + (li << 8);
#pragma unroll
            for (int kt = 0; kt < 8; ++kt) {
                bf16x8 bfr = *reinterpret_cast<const bf16x8*>(jrow + koff[kt]);
#pragma unroll
                for (int it = 0; it < 4; ++it)
                    acc[it] = __builtin_amdgcn_mfma_f32_16x16x32_bf16(
                        afrag[it][kt], bfr, acc[it], 0, 0, 0);
            }
            // C/D layout (m89-verified): col = lane&15, row = quad*4 + reg
            float cs = 0.0f;
#pragma unroll
            for (int it = 0; it < 4; ++it)
#pragma unroll
                for (int r = 0; r < 4; ++r) {
                    float e = __expf(acc[it][r] * 2.0f - 2.0f);
                    part[it][r] += e;
                    cs += e;
                }
            csum2[jtile] = cs;
        }
        // column partials: reduce over q (i-rows within wave), into LDS colsum.
#pragma unroll
        for (int jtile = 0; jtile < 2; ++jtile) {
            float v = csum2[jtile];
            v += __shfl_xor(v, 16);
            v += __shfl_xor(v, 32);
            if (q == 0) atomicAdd(&colsum[jt * TJ + jtile * 16 + li], v);
        }
        __syncthreads();   // staged tile ready; all reads of rd + colsum adds done
        const ushort* t0 = rd; rd = wr; wr = (ushort*)t0;
    }
#undef STAGE

    // Row-side: reduce across the 16 lanes holding different j-cols of the same rows.
#pragma unroll
    for (int it = 0; it < 4; ++it)
#pragma unroll
        for (int r = 0; r < 4; ++r) {
            float v = part[it][r];
            v += __shfl_xor(v, 1);
            v += __shfl_xor(v, 2);
            v += __shfl_xor(v, 4);
            v += __shfl_xor(v, 8);
            if (li == 0) atomicAdd(&rowsum[i_base + it * 16 + q * 4 + r], v);
        }

    // Col-side: transpose contribution rowsum[j] += sum_i exp(sim_ij).
    if (!diag) atomicAdd(&rowsum[j0 + tid], colsum[tid]);
}

// lse_i = 2 + log(rowsum_i - 1); loss = (sum lse - sum pos)/M.
// 32 blocks; per-block partial -> atomicAdd into pre-zeroed out[0].
__global__ void k_final(const float* __restrict__ rowsum, const float* __restrict__ pos_part,
                        float* __restrict__ out) {
    int idx = blockIdx.x * 256 + threadIdx.x;   // 0..8191
    float acc  = 2.0f + __logf(rowsum[idx] - 1.0f);
    float pacc = (idx < N_HALF) ? pos_part[idx] : 0.0f;
    acc  = wave_reduce_sum(acc);
    pacc = wave_reduce_sum(pacc);
    __shared__ float wsum[4], psum[4];
    int t = threadIdx.x;
    if ((t & 63) == 0) { wsum[t >> 6] = acc; psum[t >> 6] = pacc; }
    __syncthreads();
    if (t == 0) {
        float tot = wsum[0] + wsum[1] + wsum[2] + wsum[3]
                  - (psum[0] + psum[1] + psum[2] + psum[3]);
        atomicAdd(out, tot / (float)M_TOT);
    }
}

extern "C" void kernel_launch(void* const* d_in, const int* in_sizes, int n_in,
                              void* d_out, int out_size, void* d_ws, size_t ws_size,
                              hipStream_t stream) {
    const float* zis = (const float*)d_in[0];
    const float* zjs = (const float*)d_in[1];
    char* ws = (char*)d_ws;
    __hip_bfloat16* zn = (__hip_bfloat16*)ws;                         // 4 MB
    float* rowsum   = (float*)(ws + (size_t)M_TOT * D * 2);           // 32 KB
    float* pos_part = rowsum + M_TOT;                                 // 16 KB
    float* out = (float*)d_out;

    k_prep<<<N_HALF, 256, 0, stream>>>(zis, zjs, zn, rowsum, pos_part, out);
    k_main<<<NBLK, 256, 0, stream>>>(zn, rowsum);
    k_final<<<M_TOT / 256, 256, 0, stream>>>(rowsum, pos_part, out);
}